// Round 1
// baseline (380.799 us; speedup 1.0000x reference)
//
#include <hip/hip_runtime.h>
#include <hip/hip_bf16.h>
#include <math.h>

#define Bn 8
#define Nn 2048
#define Dn 256

typedef short short8 __attribute__((ext_vector_type(8)));
typedef short short4v __attribute__((ext_vector_type(4)));
typedef float floatx4 __attribute__((ext_vector_type(4)));

__device__ __forceinline__ short f2bf_bits(float f) {
    __bf16 h = (__bf16)f;
    return __builtin_bit_cast(short, h);
}

__device__ __forceinline__ void gl_lds16(const void* gsrc, void* ldst) {
    __builtin_amdgcn_global_load_lds(
        (const __attribute__((address_space(1))) void*)gsrc,
        (__attribute__((address_space(3))) void*)ldst, 16, 0, 0);
}

__device__ __forceinline__ float sigmoidf_(float z) {
    return 1.0f / (1.0f + __expf(-z));
}

// ---- tiny prep kernels ----------------------------------------------------

// Wt[e][d] = bf16(W_fp[d][e])   (so the GEMM B-operand is row-contiguous)
__global__ void k_transpose(const float* __restrict__ W, short* __restrict__ Wt) {
    int e = blockIdx.x, d = threadIdx.x;
    Wt[e * Dn + d] = f2bf_bits(W[d * Dn + e]);
}

// xmean[b][d] = mean over n of x[b,n,d]  (atomic partial sums over row chunks)
__global__ void k_xmean(const float* __restrict__ x, float* __restrict__ xmean) {
    int b = blockIdx.x, ch = blockIdx.y, t = threadIdx.x;
    const float* xp = x + ((size_t)b * Nn + (size_t)ch * 256) * Dn + t;
    float acc = 0.f;
    #pragma unroll 4
    for (int r = 0; r < 256; ++r) acc += xp[(size_t)r * Dn];
    atomicAdd(&xmean[b * Dn + t], acc * (1.0f / Nn));
}

// ---- K1: proj = x @ W_fp + b_fp  (bf16 MFMA), fused rowdot(w_s) + ||.||^2 --

__global__ __launch_bounds__(256) void k_proj(
    const float* __restrict__ x, const short* __restrict__ Wt,
    const float* __restrict__ b_fp, const float* __restrict__ w_s,
    float* __restrict__ proj, float* __restrict__ sdot, float* __restrict__ nrmsq) {
    __shared__ __align__(16) short As[128 * 64];
    __shared__ __align__(16) short Bs[128 * 64];
    const int t = threadIdx.x;
    const int bm = blockIdx.x * 128;   // global row in [0, B*N)
    const int cb = blockIdx.y * 128;   // output-col base
    const int lane = t & 63, wv = t >> 6;
    const int wm = (wv >> 1) * 64, wn = (wv & 1) * 64;
    const int l15 = lane & 15, q = lane >> 4;
    const int rr = t >> 3, c8 = (t & 7) * 8;

    floatx4 acc[4][4];
    #pragma unroll
    for (int i = 0; i < 4; ++i)
        #pragma unroll
        for (int j = 0; j < 4; ++j) acc[i][j] = (floatx4){0.f, 0.f, 0.f, 0.f};

    for (int k0 = 0; k0 < Dn; k0 += 64) {
        #pragma unroll
        for (int cc = 0; cc < 4; ++cc) {
            int r = cc * 32 + rr;
            // A: x fp32 -> bf16 convert into LDS
            const float* gp = x + (size_t)(bm + r) * Dn + k0 + c8;
            float4 v0 = *(const float4*)gp;
            float4 v1 = *(const float4*)(gp + 4);
            short8 o;
            o[0] = f2bf_bits(v0.x); o[1] = f2bf_bits(v0.y);
            o[2] = f2bf_bits(v0.z); o[3] = f2bf_bits(v0.w);
            o[4] = f2bf_bits(v1.x); o[5] = f2bf_bits(v1.y);
            o[6] = f2bf_bits(v1.z); o[7] = f2bf_bits(v1.w);
            *(short8*)(As + r * 64 + c8) = o;
            // B: Wt rows (already bf16) via async global->LDS
            gl_lds16(Wt + (size_t)(cb + r) * Dn + k0 + c8, Bs + r * 64 + c8);
        }
        __syncthreads();
        #pragma unroll
        for (int ks = 0; ks < 2; ++ks) {
            short8 af[4], bfr[4];
            #pragma unroll
            for (int i = 0; i < 4; ++i)
                af[i] = *(const short8*)(As + (wm + i * 16 + l15) * 64 + ks * 32 + q * 8);
            #pragma unroll
            for (int j = 0; j < 4; ++j)
                bfr[j] = *(const short8*)(Bs + (wn + j * 16 + l15) * 64 + ks * 32 + q * 8);
            #pragma unroll
            for (int i = 0; i < 4; ++i)
                #pragma unroll
                for (int j = 0; j < 4; ++j)
                    acc[i][j] = __builtin_amdgcn_mfma_f32_16x16x32_bf16(af[i], bfr[j], acc[i][j], 0, 0, 0);
        }
        __syncthreads();
    }
    // epilogue: store proj, accumulate sdot = proj.w_s and nrmsq = sum proj^2
    float wsv[4], bfv4[4];
    #pragma unroll
    for (int j = 0; j < 4; ++j) {
        int c = cb + wn + j * 16 + l15;
        wsv[j] = w_s[c];
        bfv4[j] = b_fp[c];
    }
    #pragma unroll
    for (int i = 0; i < 4; ++i) {
        #pragma unroll
        for (int reg = 0; reg < 4; ++reg) {
            int row = bm + wm + i * 16 + q * 4 + reg;
            float pw = 0.f, pn = 0.f;
            #pragma unroll
            for (int j = 0; j < 4; ++j) {
                float v = acc[i][j][reg] + bfv4[j];
                proj[(size_t)row * Dn + cb + wn + j * 16 + l15] = v;
                pw += v * wsv[j];
                pn += v * v;
            }
            #pragma unroll
            for (int m = 1; m < 16; m <<= 1) {
                pw += __shfl_xor(pw, m);
                pn += __shfl_xor(pn, m);
            }
            if (l15 == 0) {
                atomicAdd(&sdot[row], pw);
                atomicAdd(&nrmsq[row], pn);
            }
        }
    }
}

// ---- K1b: xn = bf16(proj / max(||proj||, 1e-12)) --------------------------

__global__ void k_xn(const float* __restrict__ proj, const float* __restrict__ nrmsq,
                     short* __restrict__ xn) {
    size_t idx = ((size_t)blockIdx.x * 256 + threadIdx.x) * 4;
    int row = (int)(idx >> 8);
    float inv = 1.0f / fmaxf(sqrtf(nrmsq[row]), 1e-12f);
    float4 v = *(const float4*)(proj + idx);
    short4v o;
    o[0] = f2bf_bits(v.x * inv); o[1] = f2bf_bits(v.y * inv);
    o[2] = f2bf_bits(v.z * inv); o[3] = f2bf_bits(v.w * inv);
    *(short4v*)(xn + idx) = o;
}

// ---- K2: sim = xn@xn^T, fused scaler/clamp, adj write, degree row-sums ----

__global__ __launch_bounds__(256) void k_sim(
    const short* __restrict__ xn, const float* __restrict__ sdot,
    const float* __restrict__ b_s, float* __restrict__ adj, float* __restrict__ degree) {
    __shared__ __align__(16) short As[128 * 64];
    __shared__ __align__(16) short Bs[128 * 64];
    const int t = threadIdx.x;
    const int bn = blockIdx.x * 128;   // col tile
    const int bm = blockIdx.y * 128;   // row tile
    const int b = blockIdx.z;
    const int lane = t & 63, wv = t >> 6;
    const int wm = (wv >> 1) * 64, wn = (wv & 1) * 64;
    const int l15 = lane & 15, q = lane >> 4;
    const int rr = t >> 3, c8 = (t & 7) * 8;
    const short* xb = xn + (size_t)b * Nn * Dn;

    floatx4 acc[4][4];
    #pragma unroll
    for (int i = 0; i < 4; ++i)
        #pragma unroll
        for (int j = 0; j < 4; ++j) acc[i][j] = (floatx4){0.f, 0.f, 0.f, 0.f};

    for (int k0 = 0; k0 < Dn; k0 += 64) {
        #pragma unroll
        for (int cc = 0; cc < 4; ++cc) {
            int r = cc * 32 + rr;
            gl_lds16(xb + (size_t)(bm + r) * Dn + k0 + c8, As + r * 64 + c8);
            gl_lds16(xb + (size_t)(bn + r) * Dn + k0 + c8, Bs + r * 64 + c8);
        }
        __syncthreads();
        #pragma unroll
        for (int ks = 0; ks < 2; ++ks) {
            short8 af[4], bfr[4];
            #pragma unroll
            for (int i = 0; i < 4; ++i)
                af[i] = *(const short8*)(As + (wm + i * 16 + l15) * 64 + ks * 32 + q * 8);
            #pragma unroll
            for (int j = 0; j < 4; ++j)
                bfr[j] = *(const short8*)(Bs + (wn + j * 16 + l15) * 64 + ks * 32 + q * 8);
            #pragma unroll
            for (int i = 0; i < 4; ++i)
                #pragma unroll
                for (int j = 0; j < 4; ++j)
                    acc[i][j] = __builtin_amdgcn_mfma_f32_16x16x32_bf16(af[i], bfr[j], acc[i][j], 0, 0, 0);
        }
        __syncthreads();
    }
    // epilogue
    const float bsv = b_s[0];
    float scol[4];
    #pragma unroll
    for (int j = 0; j < 4; ++j)
        scol[j] = sigmoidf_(sdot[b * Nn + bn + wn + j * 16 + l15] + bsv);
    #pragma unroll
    for (int i = 0; i < 4; ++i) {
        #pragma unroll
        for (int reg = 0; reg < 4; ++reg) {
            int row = bm + wm + i * 16 + q * 4 + reg;
            float srow = sigmoidf_(sdot[b * Nn + row] + bsv);
            size_t obase = ((size_t)b * Nn + row) * Nn + bn + wn + l15;
            float rs = 0.f;
            #pragma unroll
            for (int j = 0; j < 4; ++j) {
                float sc = 0.5f * (srow + scol[j]);
                sc = fminf(fmaxf(sc, 1e-6f), 1.0f);
                float v = fmaxf(sc * acc[i][j][reg], 1e-6f);
                adj[obase + (size_t)j * 16] = v;
                rs += v;
            }
            #pragma unroll
            for (int m = 1; m < 16; m <<= 1) rs += __shfl_xor(rs, m);
            if (l15 == 0) atomicAdd(&degree[b * Nn + row], rs);
        }
    }
}

// ---- K3: colsum[b,m] = sum_n adj[b,n,m] / max(degree[b,n],1e-6) -----------

__global__ void k_colsum(const float* __restrict__ adj, const float* __restrict__ degree,
                         float* __restrict__ colsum) {
    int b = blockIdx.x, cbk = blockIdx.y, rc = blockIdx.z;
    int t = threadIdx.x;
    __shared__ float inv[32];
    if (t < 32) inv[t] = 1.0f / fmaxf(degree[b * Nn + rc * 32 + t], 1e-6f);
    __syncthreads();
    int c = cbk * 1024 + t * 4;
    const float* ap = adj + ((size_t)b * Nn + (size_t)rc * 32) * Nn + c;
    float sx = 0.f, sy = 0.f, sz = 0.f, sw = 0.f;
    #pragma unroll 4
    for (int r = 0; r < 32; ++r) {
        float4 v = *(const float4*)(ap + (size_t)r * Nn);
        float w = inv[r];
        sx += v.x * w; sy += v.y * w; sz += v.z * w; sw += v.w * w;
    }
    atomicAdd(&colsum[b * Nn + c + 0], sx);
    atomicAdd(&colsum[b * Nn + c + 1], sy);
    atomicAdd(&colsum[b * Nn + c + 2], sz);
    atomicAdd(&colsum[b * Nn + c + 3], sw);
}

// ---- K4: g_pre -> W_rp -> W_gp -> +xmean -> LayerNorm -> out --------------

__global__ __launch_bounds__(256) void k_final(
    const float* __restrict__ proj, const float* __restrict__ colsum,
    const float* __restrict__ xmean,
    const float* __restrict__ W_rp, const float* __restrict__ b_rp,
    const float* __restrict__ W_gp, const float* __restrict__ b_gp,
    const float* __restrict__ gamma, const float* __restrict__ beta,
    float* __restrict__ out) {
    int b = blockIdx.x, t = threadIdx.x;
    __shared__ float cs[Nn];
    __shared__ float gp_s[Dn];
    __shared__ float g1_s[Dn];
    __shared__ float red[8];
    for (int i = t; i < Nn; i += 256) cs[i] = colsum[b * Nn + i];
    __syncthreads();
    // g_pre[t] = (1/N) sum_m cs[m] * proj[b,m,t]
    const float* pp = proj + (size_t)b * Nn * Dn + t;
    float a0 = 0.f, a1 = 0.f, a2 = 0.f, a3 = 0.f;
    for (int m = 0; m < Nn; m += 4) {
        a0 += cs[m + 0] * pp[(size_t)(m + 0) * Dn];
        a1 += cs[m + 1] * pp[(size_t)(m + 1) * Dn];
        a2 += cs[m + 2] * pp[(size_t)(m + 2) * Dn];
        a3 += cs[m + 3] * pp[(size_t)(m + 3) * Dn];
    }
    gp_s[t] = ((a0 + a1) + (a2 + a3)) * (1.0f / Nn);
    __syncthreads();
    float g1 = b_rp[t];
    #pragma unroll 4
    for (int d = 0; d < Dn; ++d) g1 += gp_s[d] * W_rp[d * Dn + t];
    g1_s[t] = g1;
    __syncthreads();
    float g2 = b_gp[t];
    #pragma unroll 4
    for (int e = 0; e < Dn; ++e) g2 += g1_s[e] * W_gp[e * Dn + t];
    float h = g2 + xmean[b * Dn + t];
    // LayerNorm over D=256
    float sum = h;
    #pragma unroll
    for (int m = 1; m < 64; m <<= 1) sum += __shfl_xor(sum, m);
    if ((t & 63) == 0) red[t >> 6] = sum;
    __syncthreads();
    float mu = (red[0] + red[1] + red[2] + red[3]) * (1.0f / Dn);
    float dv = h - mu;
    float s2 = dv * dv;
    #pragma unroll
    for (int m = 1; m < 64; m <<= 1) s2 += __shfl_xor(s2, m);
    if ((t & 63) == 0) red[4 + (t >> 6)] = s2;
    __syncthreads();
    float var = (red[4] + red[5] + red[6] + red[7]) * (1.0f / Dn);
    out[b * Dn + t] = dv * rsqrtf(var + 1e-5f) * gamma[t] + beta[t];
}

// ---- launcher --------------------------------------------------------------

extern "C" void kernel_launch(void* const* d_in, const int* in_sizes, int n_in,
                              void* d_out, int out_size, void* d_ws, size_t ws_size,
                              hipStream_t stream) {
    const float* x     = (const float*)d_in[0];
    const float* W_fp  = (const float*)d_in[1];
    const float* b_fp  = (const float*)d_in[2];
    const float* w_s   = (const float*)d_in[3];
    const float* b_s   = (const float*)d_in[4];
    const float* W_rp  = (const float*)d_in[5];
    const float* b_rp  = (const float*)d_in[6];
    const float* W_gp  = (const float*)d_in[7];
    const float* b_gp  = (const float*)d_in[8];
    const float* gamma = (const float*)d_in[9];
    const float* beta  = (const float*)d_in[10];

    float* out = (float*)d_out;
    float* adj = out + Bn * Dn;   // outputs concatenated: out (B*D) then adj (B*N*N)

    char* ws = (char*)d_ws;
    float* proj   = (float*)(ws);                    // 16 MB
    short* xn     = (short*)(ws + 16777216);         // 8 MB (bf16 bits)
    short* Wt     = (short*)(ws + 25165824);         // 128 KB
    float* sdot   = (float*)(ws + 25296896);         // 64 KB
    float* nrmsq  = (float*)(ws + 25362432);         // 64 KB
    float* degree = (float*)(ws + 25427968);         // 64 KB
    float* colsum = (float*)(ws + 25493504);         // 64 KB
    float* xmean  = (float*)(ws + 25559040);         // 8 KB

    // zero the atomic accumulators (sdot..xmean contiguous)
    hipMemsetAsync(ws + 25296896, 0, 270336, stream);

    k_transpose<<<Dn, Dn, 0, stream>>>(W_fp, Wt);
    k_xmean<<<dim3(Bn, 8), Dn, 0, stream>>>(x, xmean);
    k_proj<<<dim3((Bn * Nn) / 128, 2), 256, 0, stream>>>(x, Wt, b_fp, w_s, proj, sdot, nrmsq);
    k_xn<<<(Bn * Nn * Dn) / 1024, 256, 0, stream>>>(proj, nrmsq, xn);
    k_sim<<<dim3(Nn / 128, Nn / 128, Bn), 256, 0, stream>>>(xn, sdot, b_s, adj, degree);
    k_colsum<<<dim3(Bn, 2, 64), 256, 0, stream>>>(adj, degree, colsum);
    k_final<<<Bn, 256, 0, stream>>>(proj, colsum, xmean, W_rp, b_rp, W_gp, b_gp, gamma, beta, out);
}

// Round 2
// 321.479 us; speedup vs baseline: 1.1845x; 1.1845x over previous
//
#include <hip/hip_runtime.h>
#include <hip/hip_bf16.h>
#include <math.h>

#define Bn 8
#define Nn 2048
#define Dn 256

typedef short short8 __attribute__((ext_vector_type(8)));
typedef short short4v __attribute__((ext_vector_type(4)));
typedef float floatx4 __attribute__((ext_vector_type(4)));

__device__ __forceinline__ short f2bf_bits(float f) {
    __bf16 h = (__bf16)f;
    return __builtin_bit_cast(short, h);
}

__device__ __forceinline__ void gl_lds16(const void* gsrc, void* ldst) {
    __builtin_amdgcn_global_load_lds(
        (const __attribute__((address_space(1))) void*)gsrc,
        (__attribute__((address_space(3))) void*)ldst, 16, 0, 0);
}

__device__ __forceinline__ float sigmoidf_(float z) {
    return 1.0f / (1.0f + __expf(-z));
}

// ---- tiny prep kernels ----------------------------------------------------

// Wt[e][d] = bf16(W_fp[d][e])   (so the GEMM B-operand is row-contiguous)
__global__ void k_transpose(const float* __restrict__ W, short* __restrict__ Wt) {
    int e = blockIdx.x, d = threadIdx.x;
    Wt[e * Dn + d] = f2bf_bits(W[d * Dn + e]);
}

// xmean[b][d] = mean over n of x[b,n,d]  (atomic partial sums over 64-row chunks)
__global__ void k_xmean(const float* __restrict__ x, float* __restrict__ xmean) {
    int b = blockIdx.x, ch = blockIdx.y, t = threadIdx.x;
    const float* xp = x + ((size_t)b * Nn + (size_t)ch * 64) * Dn + t;
    float acc = 0.f;
    #pragma unroll 4
    for (int r = 0; r < 64; ++r) acc += xp[(size_t)r * Dn];
    atomicAdd(&xmean[b * Dn + t], acc * (1.0f / Nn));
}

// ---- K1: proj = x @ W_fp + b_fp  (bf16 MFMA), fused rowdot(w_s) + ||.||^2 --

__global__ __launch_bounds__(256) void k_proj(
    const float* __restrict__ x, const short* __restrict__ Wt,
    const float* __restrict__ b_fp, const float* __restrict__ w_s,
    float* __restrict__ proj, float* __restrict__ sdot, float* __restrict__ nrmsq) {
    __shared__ __align__(16) short As[128 * 64];
    __shared__ __align__(16) short Bs[128 * 64];
    const int t = threadIdx.x;
    const int bm = blockIdx.x * 128;   // global row in [0, B*N)
    const int cb = blockIdx.y * 128;   // output-col base
    const int lane = t & 63, wv = t >> 6;
    const int wm = (wv >> 1) * 64, wn = (wv & 1) * 64;
    const int l15 = lane & 15, q = lane >> 4;
    const int rr = t >> 3, c8 = (t & 7) * 8;

    floatx4 acc[4][4];
    #pragma unroll
    for (int i = 0; i < 4; ++i)
        #pragma unroll
        for (int j = 0; j < 4; ++j) acc[i][j] = (floatx4){0.f, 0.f, 0.f, 0.f};

    for (int k0 = 0; k0 < Dn; k0 += 64) {
        #pragma unroll
        for (int cc = 0; cc < 4; ++cc) {
            int r = cc * 32 + rr;
            // A: x fp32 -> bf16 convert into LDS
            const float* gp = x + (size_t)(bm + r) * Dn + k0 + c8;
            float4 v0 = *(const float4*)gp;
            float4 v1 = *(const float4*)(gp + 4);
            short8 o;
            o[0] = f2bf_bits(v0.x); o[1] = f2bf_bits(v0.y);
            o[2] = f2bf_bits(v0.z); o[3] = f2bf_bits(v0.w);
            o[4] = f2bf_bits(v1.x); o[5] = f2bf_bits(v1.y);
            o[6] = f2bf_bits(v1.z); o[7] = f2bf_bits(v1.w);
            *(short8*)(As + r * 64 + c8) = o;
            // B: Wt rows (already bf16) via async global->LDS
            gl_lds16(Wt + (size_t)(cb + r) * Dn + k0 + c8, Bs + r * 64 + c8);
        }
        __syncthreads();
        #pragma unroll
        for (int ks = 0; ks < 2; ++ks) {
            short8 af[4], bfr[4];
            #pragma unroll
            for (int i = 0; i < 4; ++i)
                af[i] = *(const short8*)(As + (wm + i * 16 + l15) * 64 + ks * 32 + q * 8);
            #pragma unroll
            for (int j = 0; j < 4; ++j)
                bfr[j] = *(const short8*)(Bs + (wn + j * 16 + l15) * 64 + ks * 32 + q * 8);
            #pragma unroll
            for (int i = 0; i < 4; ++i)
                #pragma unroll
                for (int j = 0; j < 4; ++j)
                    acc[i][j] = __builtin_amdgcn_mfma_f32_16x16x32_bf16(af[i], bfr[j], acc[i][j], 0, 0, 0);
        }
        __syncthreads();
    }
    // epilogue: store proj, accumulate sdot = proj.w_s and nrmsq = sum proj^2
    float wsv[4], bfv4[4];
    #pragma unroll
    for (int j = 0; j < 4; ++j) {
        int c = cb + wn + j * 16 + l15;
        wsv[j] = w_s[c];
        bfv4[j] = b_fp[c];
    }
    #pragma unroll
    for (int i = 0; i < 4; ++i) {
        #pragma unroll
        for (int reg = 0; reg < 4; ++reg) {
            int row = bm + wm + i * 16 + q * 4 + reg;
            float pw = 0.f, pn = 0.f;
            #pragma unroll
            for (int j = 0; j < 4; ++j) {
                float v = acc[i][j][reg] + bfv4[j];
                proj[(size_t)row * Dn + cb + wn + j * 16 + l15] = v;
                pw += v * wsv[j];
                pn += v * v;
            }
            #pragma unroll
            for (int m = 1; m < 16; m <<= 1) {
                pw += __shfl_xor(pw, m);
                pn += __shfl_xor(pn, m);
            }
            if (l15 == 0) {
                atomicAdd(&sdot[row], pw);
                atomicAdd(&nrmsq[row], pn);
            }
        }
    }
}

// ---- K1b: xn = bf16(proj / max(||proj||, 1e-12)) --------------------------

__global__ void k_xn(const float* __restrict__ proj, const float* __restrict__ nrmsq,
                     short* __restrict__ xn) {
    size_t idx = ((size_t)blockIdx.x * 256 + threadIdx.x) * 4;
    int row = (int)(idx >> 8);
    float inv = 1.0f / fmaxf(sqrtf(nrmsq[row]), 1e-12f);
    float4 v = *(const float4*)(proj + idx);
    short4v o;
    o[0] = f2bf_bits(v.x * inv); o[1] = f2bf_bits(v.y * inv);
    o[2] = f2bf_bits(v.z * inv); o[3] = f2bf_bits(v.w * inv);
    *(short4v*)(xn + idx) = o;
}

// ---- K2: sim = xn@xn^T, fused scaler/clamp, adj write, degree row-sums ----

__global__ __launch_bounds__(256) void k_sim(
    const short* __restrict__ xn, const float* __restrict__ sdot,
    const float* __restrict__ b_s, float* __restrict__ adj, float* __restrict__ degree) {
    __shared__ __align__(16) short As[128 * 64];
    __shared__ __align__(16) short Bs[128 * 64];
    const int t = threadIdx.x;
    const int bn = blockIdx.x * 128;   // col tile
    const int bm = blockIdx.y * 128;   // row tile
    const int b = blockIdx.z;
    const int lane = t & 63, wv = t >> 6;
    const int wm = (wv >> 1) * 64, wn = (wv & 1) * 64;
    const int l15 = lane & 15, q = lane >> 4;
    const int rr = t >> 3, c8 = (t & 7) * 8;
    const short* xb = xn + (size_t)b * Nn * Dn;

    floatx4 acc[4][4];
    #pragma unroll
    for (int i = 0; i < 4; ++i)
        #pragma unroll
        for (int j = 0; j < 4; ++j) acc[i][j] = (floatx4){0.f, 0.f, 0.f, 0.f};

    for (int k0 = 0; k0 < Dn; k0 += 64) {
        #pragma unroll
        for (int cc = 0; cc < 4; ++cc) {
            int r = cc * 32 + rr;
            gl_lds16(xb + (size_t)(bm + r) * Dn + k0 + c8, As + r * 64 + c8);
            gl_lds16(xb + (size_t)(bn + r) * Dn + k0 + c8, Bs + r * 64 + c8);
        }
        __syncthreads();
        #pragma unroll
        for (int ks = 0; ks < 2; ++ks) {
            short8 af[4], bfr[4];
            #pragma unroll
            for (int i = 0; i < 4; ++i)
                af[i] = *(const short8*)(As + (wm + i * 16 + l15) * 64 + ks * 32 + q * 8);
            #pragma unroll
            for (int j = 0; j < 4; ++j)
                bfr[j] = *(const short8*)(Bs + (wn + j * 16 + l15) * 64 + ks * 32 + q * 8);
            #pragma unroll
            for (int i = 0; i < 4; ++i)
                #pragma unroll
                for (int j = 0; j < 4; ++j)
                    acc[i][j] = __builtin_amdgcn_mfma_f32_16x16x32_bf16(af[i], bfr[j], acc[i][j], 0, 0, 0);
        }
        __syncthreads();
    }
    // epilogue
    const float bsv = b_s[0];
    float scol[4];
    #pragma unroll
    for (int j = 0; j < 4; ++j)
        scol[j] = sigmoidf_(sdot[b * Nn + bn + wn + j * 16 + l15] + bsv);
    #pragma unroll
    for (int i = 0; i < 4; ++i) {
        #pragma unroll
        for (int reg = 0; reg < 4; ++reg) {
            int row = bm + wm + i * 16 + q * 4 + reg;
            float srow = sigmoidf_(sdot[b * Nn + row] + bsv);
            size_t obase = ((size_t)b * Nn + row) * Nn + bn + wn + l15;
            float rs = 0.f;
            #pragma unroll
            for (int j = 0; j < 4; ++j) {
                float sc = 0.5f * (srow + scol[j]);
                sc = fminf(fmaxf(sc, 1e-6f), 1.0f);
                float v = fmaxf(sc * acc[i][j][reg], 1e-6f);
                adj[obase + (size_t)j * 16] = v;
                rs += v;
            }
            #pragma unroll
            for (int m = 1; m < 16; m <<= 1) rs += __shfl_xor(rs, m);
            if (l15 == 0) atomicAdd(&degree[b * Nn + row], rs);
        }
    }
}

// ---- K3: colsum[b,m] = sum_n adj[b,n,m] / max(degree[b,n],1e-6) -----------

__global__ void k_colsum(const float* __restrict__ adj, const float* __restrict__ degree,
                         float* __restrict__ colsum) {
    int b = blockIdx.x, cbk = blockIdx.y, rc = blockIdx.z;
    int t = threadIdx.x;
    __shared__ float inv[32];
    if (t < 32) inv[t] = 1.0f / fmaxf(degree[b * Nn + rc * 32 + t], 1e-6f);
    __syncthreads();
    int c = cbk * 1024 + t * 4;
    const float* ap = adj + ((size_t)b * Nn + (size_t)rc * 32) * Nn + c;
    float sx = 0.f, sy = 0.f, sz = 0.f, sw = 0.f;
    #pragma unroll 4
    for (int r = 0; r < 32; ++r) {
        float4 v = *(const float4*)(ap + (size_t)r * Nn);
        float w = inv[r];
        sx += v.x * w; sy += v.y * w; sz += v.z * w; sw += v.w * w;
    }
    atomicAdd(&colsum[b * Nn + c + 0], sx);
    atomicAdd(&colsum[b * Nn + c + 1], sy);
    atomicAdd(&colsum[b * Nn + c + 2], sz);
    atomicAdd(&colsum[b * Nn + c + 3], sw);
}

// ---- K4a: gpre[b,d] = sum_m colsum[b,m] * proj[b,m,d]  (parallel, atomic) --

__global__ __launch_bounds__(256) void k_gpre(
    const float* __restrict__ proj, const float* __restrict__ colsum,
    float* __restrict__ gpre) {
    int b = blockIdx.x, ch = blockIdx.y, t = threadIdx.x;
    __shared__ float cs[64];
    if (t < 64) cs[t] = colsum[b * Nn + ch * 64 + t];
    __syncthreads();
    const float* pp = proj + ((size_t)b * Nn + (size_t)ch * 64) * Dn + t;
    float a0 = 0.f, a1 = 0.f, a2 = 0.f, a3 = 0.f;
    #pragma unroll 4
    for (int r = 0; r < 64; r += 4) {
        a0 += cs[r + 0] * pp[(size_t)(r + 0) * Dn];
        a1 += cs[r + 1] * pp[(size_t)(r + 1) * Dn];
        a2 += cs[r + 2] * pp[(size_t)(r + 2) * Dn];
        a3 += cs[r + 3] * pp[(size_t)(r + 3) * Dn];
    }
    atomicAdd(&gpre[b * Dn + t], (a0 + a1) + (a2 + a3));
}

// ---- K4b: gpre -> W_rp -> W_gp -> +xmean -> LayerNorm -> out --------------

__global__ __launch_bounds__(256) void k_final2(
    const float* __restrict__ gpre, const float* __restrict__ xmean,
    const float* __restrict__ W_rp, const float* __restrict__ b_rp,
    const float* __restrict__ W_gp, const float* __restrict__ b_gp,
    const float* __restrict__ gamma, const float* __restrict__ beta,
    float* __restrict__ out) {
    int b = blockIdx.x, t = threadIdx.x;
    __shared__ float gp_s[Dn];
    __shared__ float g1_s[Dn];
    __shared__ float red[8];
    gp_s[t] = gpre[b * Dn + t] * (1.0f / Nn);
    __syncthreads();
    float g1 = b_rp[t];
    #pragma unroll 4
    for (int d = 0; d < Dn; ++d) g1 += gp_s[d] * W_rp[d * Dn + t];
    g1_s[t] = g1;
    __syncthreads();
    float g2 = b_gp[t];
    #pragma unroll 4
    for (int e = 0; e < Dn; ++e) g2 += g1_s[e] * W_gp[e * Dn + t];
    float h = g2 + xmean[b * Dn + t];
    // LayerNorm over D=256
    float sum = h;
    #pragma unroll
    for (int m = 1; m < 64; m <<= 1) sum += __shfl_xor(sum, m);
    if ((t & 63) == 0) red[t >> 6] = sum;
    __syncthreads();
    float mu = (red[0] + red[1] + red[2] + red[3]) * (1.0f / Dn);
    float dv = h - mu;
    float s2 = dv * dv;
    #pragma unroll
    for (int m = 1; m < 64; m <<= 1) s2 += __shfl_xor(s2, m);
    if ((t & 63) == 0) red[4 + (t >> 6)] = s2;
    __syncthreads();
    float var = (red[4] + red[5] + red[6] + red[7]) * (1.0f / Dn);
    out[b * Dn + t] = dv * rsqrtf(var + 1e-5f) * gamma[t] + beta[t];
}

// ---- launcher --------------------------------------------------------------

extern "C" void kernel_launch(void* const* d_in, const int* in_sizes, int n_in,
                              void* d_out, int out_size, void* d_ws, size_t ws_size,
                              hipStream_t stream) {
    const float* x     = (const float*)d_in[0];
    const float* W_fp  = (const float*)d_in[1];
    const float* b_fp  = (const float*)d_in[2];
    const float* w_s   = (const float*)d_in[3];
    const float* b_s   = (const float*)d_in[4];
    const float* W_rp  = (const float*)d_in[5];
    const float* b_rp  = (const float*)d_in[6];
    const float* W_gp  = (const float*)d_in[7];
    const float* b_gp  = (const float*)d_in[8];
    const float* gamma = (const float*)d_in[9];
    const float* beta  = (const float*)d_in[10];

    float* out = (float*)d_out;
    float* adj = out + Bn * Dn;   // outputs concatenated: out (B*D) then adj (B*N*N)

    char* ws = (char*)d_ws;
    float* proj   = (float*)(ws);                    // 16 MB
    short* xn     = (short*)(ws + 16777216);         // 8 MB (bf16 bits)
    short* Wt     = (short*)(ws + 25165824);         // 128 KB
    float* sdot   = (float*)(ws + 25296896);         // 64 KB
    float* nrmsq  = (float*)(ws + 25362432);         // 64 KB
    float* degree = (float*)(ws + 25427968);         // 64 KB
    float* colsum = (float*)(ws + 25493504);         // 64 KB
    float* xmean  = (float*)(ws + 25559040);         // 8 KB
    float* gpre   = (float*)(ws + 25567232);         // 8 KB

    // zero the atomic accumulators (sdot..gpre contiguous)
    hipMemsetAsync(ws + 25296896, 0, 278528, stream);

    k_transpose<<<Dn, Dn, 0, stream>>>(W_fp, Wt);
    k_xmean<<<dim3(Bn, 32), Dn, 0, stream>>>(x, xmean);
    k_proj<<<dim3((Bn * Nn) / 128, 2), 256, 0, stream>>>(x, Wt, b_fp, w_s, proj, sdot, nrmsq);
    k_xn<<<(Bn * Nn * Dn) / 1024, 256, 0, stream>>>(proj, nrmsq, xn);
    k_sim<<<dim3(Nn / 128, Nn / 128, Bn), 256, 0, stream>>>(xn, sdot, b_s, adj, degree);
    k_colsum<<<dim3(Bn, 2, 64), 256, 0, stream>>>(adj, degree, colsum);
    k_gpre<<<dim3(Bn, 32), 256, 0, stream>>>(proj, colsum, gpre);
    k_final2<<<Bn, 256, 0, stream>>>(gpre, xmean, W_rp, b_rp, W_gp, b_gp, gamma, beta, out);
}

// Round 3
// 315.646 us; speedup vs baseline: 1.2064x; 1.0185x over previous
//
#include <hip/hip_runtime.h>
#include <hip/hip_bf16.h>
#include <math.h>

#define Bn 8
#define Nn 2048
#define Dn 256

typedef short short8 __attribute__((ext_vector_type(8)));
typedef float floatx4 __attribute__((ext_vector_type(4)));

__device__ __forceinline__ short f2bf_bits(float f) {
    __bf16 h = (__bf16)f;
    return __builtin_bit_cast(short, h);
}

__device__ __forceinline__ float bf2f(short s) {
    unsigned u = ((unsigned)(unsigned short)s) << 16;
    return __builtin_bit_cast(float, u);
}

__device__ __forceinline__ void gl_lds16(const void* gsrc, void* ldst) {
    __builtin_amdgcn_global_load_lds(
        (const __attribute__((address_space(1))) void*)gsrc,
        (__attribute__((address_space(3))) void*)ldst, 16, 0, 0);
}

__device__ __forceinline__ float sigmoidf_(float z) {
    return 1.0f / (1.0f + __expf(-z));
}

// ---- Wt[e][d] = bf16(W_fp[d][e]) ------------------------------------------

__global__ void k_transpose(const float* __restrict__ W, short* __restrict__ Wt) {
    int e = blockIdx.x, d = threadIdx.x;
    Wt[e * Dn + d] = f2bf_bits(W[d * Dn + e]);
}

// ---- xpart[b][ch][d] = sum over 64 rows of x (no atomics) ------------------

__global__ void k_xpart(const float* __restrict__ x, float* __restrict__ xpart) {
    int b = blockIdx.x, ch = blockIdx.y, t = threadIdx.x;
    const float* xp = x + ((size_t)b * Nn + (size_t)ch * 64) * Dn + t;
    float acc = 0.f;
    #pragma unroll 4
    for (int r = 0; r < 64; ++r) acc += xp[(size_t)r * Dn];
    xpart[(b * 32 + ch) * Dn + t] = acc;
}

// ---- K1: proj rows (64 x 256 per block) via MFMA; fused norm, xn, sdot -----
// Each wave computes 16 full rows (all 256 cols) -> row norm + w_s dot +
// bf16 conversion entirely in-register. No atomics, no nrmsq buffer, no k_xn.

__global__ __launch_bounds__(256) void k_projxn(
    const float* __restrict__ x, const short* __restrict__ Wt,
    const float* __restrict__ b_fp, const float* __restrict__ w_s,
    short* __restrict__ proj_bf, short* __restrict__ xn, float* __restrict__ sdot) {
    __shared__ __align__(16) short As[64 * 64];    // 8 KB
    __shared__ __align__(16) short Bs[256 * 64];   // 32 KB
    const int t = threadIdx.x;
    const int bm = blockIdx.x * 64;                // global row base in [0, B*N)
    const int lane = t & 63, wv = t >> 6;
    const int wm = wv * 16;                        // wave's 16-row slab
    const int l15 = lane & 15, q = lane >> 4;

    floatx4 acc[16];
    #pragma unroll
    for (int j = 0; j < 16; ++j) acc[j] = (floatx4){0.f, 0.f, 0.f, 0.f};

    const int rA = t >> 2, cA = (t & 3) * 16;      // A staging map
    const int rB = t >> 3, cB = (t & 7) * 8;       // B staging map

    for (int k0 = 0; k0 < Dn; k0 += 64) {
        // A: 64x64 fp32 -> bf16
        const float* gp = x + (size_t)(bm + rA) * Dn + k0 + cA;
        float4 v0 = *(const float4*)gp;
        float4 v1 = *(const float4*)(gp + 4);
        float4 v2 = *(const float4*)(gp + 8);
        float4 v3 = *(const float4*)(gp + 12);
        short8 o0, o1;
        o0[0] = f2bf_bits(v0.x); o0[1] = f2bf_bits(v0.y);
        o0[2] = f2bf_bits(v0.z); o0[3] = f2bf_bits(v0.w);
        o0[4] = f2bf_bits(v1.x); o0[5] = f2bf_bits(v1.y);
        o0[6] = f2bf_bits(v1.z); o0[7] = f2bf_bits(v1.w);
        o1[0] = f2bf_bits(v2.x); o1[1] = f2bf_bits(v2.y);
        o1[2] = f2bf_bits(v2.z); o1[3] = f2bf_bits(v2.w);
        o1[4] = f2bf_bits(v3.x); o1[5] = f2bf_bits(v3.y);
        o1[6] = f2bf_bits(v3.z); o1[7] = f2bf_bits(v3.w);
        *(short8*)(As + rA * 64 + cA) = o0;
        *(short8*)(As + rA * 64 + cA + 8) = o1;
        // B: Wt slice 256x64 via async global->LDS (lane-contiguous layout)
        #pragma unroll
        for (int cc = 0; cc < 8; ++cc)
            gl_lds16(Wt + (size_t)(cc * 32 + rB) * Dn + k0 + cB,
                     Bs + (cc * 32 + rB) * 64 + cB);
        __syncthreads();
        #pragma unroll
        for (int ks = 0; ks < 2; ++ks) {
            short8 af = *(const short8*)(As + (wm + l15) * 64 + ks * 32 + q * 8);
            #pragma unroll
            for (int j = 0; j < 16; ++j) {
                short8 bfr = *(const short8*)(Bs + (j * 16 + l15) * 64 + ks * 32 + q * 8);
                acc[j] = __builtin_amdgcn_mfma_f32_16x16x32_bf16(af, bfr, acc[j], 0, 0, 0);
            }
        }
        __syncthreads();
    }
    // epilogue: per (reg) one full row per 16-lane group
    float bfv[16], wsv[16];
    #pragma unroll
    for (int j = 0; j < 16; ++j) {
        bfv[j] = b_fp[j * 16 + l15];
        wsv[j] = w_s[j * 16 + l15];
    }
    #pragma unroll
    for (int reg = 0; reg < 4; ++reg) {
        int row = bm + wm + q * 4 + reg;
        float v[16];
        float pw = 0.f, pn = 0.f;
        #pragma unroll
        for (int j = 0; j < 16; ++j) {
            v[j] = acc[j][reg] + bfv[j];
            pw += v[j] * wsv[j];
            pn += v[j] * v[j];
        }
        #pragma unroll
        for (int m = 1; m < 16; m <<= 1) {
            pw += __shfl_xor(pw, m);
            pn += __shfl_xor(pn, m);
        }
        float inv = 1.0f / fmaxf(sqrtf(pn), 1e-12f);
        size_t rbase = (size_t)row * Dn + l15;
        #pragma unroll
        for (int j = 0; j < 16; ++j) {
            xn[rbase + j * 16] = f2bf_bits(v[j] * inv);
            proj_bf[rbase + j * 16] = f2bf_bits(v[j]);
        }
        if (l15 == 0) sdot[row] = pw;
    }
}

// ---- K2: sim = xn@xn^T, scaler/clamp, adj write, per-tile degree partials --

__global__ __launch_bounds__(256) void k_sim(
    const short* __restrict__ xn, const float* __restrict__ sdot,
    const float* __restrict__ b_s, float* __restrict__ adj,
    float* __restrict__ deg_part) {
    __shared__ __align__(16) short As[128 * 64];
    __shared__ __align__(16) short Bs[128 * 64];
    __shared__ float degS[2][128];
    const int t = threadIdx.x;
    const int cx = blockIdx.x;
    const int bn = cx * 128;           // col tile
    const int bm = blockIdx.y * 128;   // row tile
    const int b = blockIdx.z;
    const int lane = t & 63, wv = t >> 6;
    const int wm = (wv >> 1) * 64, wn = (wv & 1) * 64;
    const int l15 = lane & 15, q = lane >> 4;
    const int rr = t >> 3, c8 = (t & 7) * 8;
    const short* xb = xn + (size_t)b * Nn * Dn;

    floatx4 acc[4][4];
    #pragma unroll
    for (int i = 0; i < 4; ++i)
        #pragma unroll
        for (int j = 0; j < 4; ++j) acc[i][j] = (floatx4){0.f, 0.f, 0.f, 0.f};

    for (int k0 = 0; k0 < Dn; k0 += 64) {
        #pragma unroll
        for (int cc = 0; cc < 4; ++cc) {
            int r = cc * 32 + rr;
            gl_lds16(xb + (size_t)(bm + r) * Dn + k0 + c8, As + r * 64 + c8);
            gl_lds16(xb + (size_t)(bn + r) * Dn + k0 + c8, Bs + r * 64 + c8);
        }
        __syncthreads();
        #pragma unroll
        for (int ks = 0; ks < 2; ++ks) {
            short8 af[4], bfr[4];
            #pragma unroll
            for (int i = 0; i < 4; ++i)
                af[i] = *(const short8*)(As + (wm + i * 16 + l15) * 64 + ks * 32 + q * 8);
            #pragma unroll
            for (int j = 0; j < 4; ++j)
                bfr[j] = *(const short8*)(Bs + (wn + j * 16 + l15) * 64 + ks * 32 + q * 8);
            #pragma unroll
            for (int i = 0; i < 4; ++i)
                #pragma unroll
                for (int j = 0; j < 4; ++j)
                    acc[i][j] = __builtin_amdgcn_mfma_f32_16x16x32_bf16(af[i], bfr[j], acc[i][j], 0, 0, 0);
        }
        __syncthreads();
    }
    // epilogue
    const float bsv = b_s[0];
    float scol[4];
    #pragma unroll
    for (int j = 0; j < 4; ++j)
        scol[j] = sigmoidf_(sdot[b * Nn + bn + wn + j * 16 + l15] + bsv);
    #pragma unroll
    for (int i = 0; i < 4; ++i) {
        #pragma unroll
        for (int reg = 0; reg < 4; ++reg) {
            int lr = wm + i * 16 + q * 4 + reg;     // local row 0..127
            int row = bm + lr;
            float srow = sigmoidf_(sdot[b * Nn + row] + bsv);
            size_t obase = ((size_t)b * Nn + row) * Nn + bn + wn + l15;
            float rs = 0.f;
            #pragma unroll
            for (int j = 0; j < 4; ++j) {
                float sc = 0.5f * (srow + scol[j]);
                sc = fminf(fmaxf(sc, 1e-6f), 1.0f);
                float v = fmaxf(sc * acc[i][j][reg], 1e-6f);
                adj[obase + (size_t)j * 16] = v;
                rs += v;
            }
            #pragma unroll
            for (int m = 1; m < 16; m <<= 1) rs += __shfl_xor(rs, m);
            if (l15 == 0) degS[wv & 1][lr] = rs;
        }
    }
    __syncthreads();
    if (t < 128)
        deg_part[((size_t)(b * 16 + cx)) * Nn + bm + t] = degS[0][t] + degS[1][t];
}

// ---- K3: colsum (no atomics) + fused gpre partial --------------------------
// block (b, ck): cols ck*64..+63, all 2048 rows. invdeg built in-block from
// the 16 degree partials. Then gpart[b][ck][d] = sum_{m in chunk} cs[m]*proj[m,d].

__global__ __launch_bounds__(256) void k_colsum(
    const float* __restrict__ adj, const float* __restrict__ deg_part,
    const short* __restrict__ proj_bf,
    float* __restrict__ colsum, float* __restrict__ gpart) {
    int b = blockIdx.x, ck = blockIdx.y, t = threadIdx.x;
    __shared__ float invdeg[Nn];        // 8 KB
    __shared__ float part[16][64];      // 4 KB
    __shared__ float csL[64];
    #pragma unroll
    for (int rc = 0; rc < 8; ++rc) {
        int row = rc * 256 + t;
        float s = 0.f;
        #pragma unroll
        for (int cx = 0; cx < 16; ++cx)
            s += deg_part[((size_t)(b * 16 + cx)) * Nn + row];
        invdeg[row] = 1.0f / fmaxf(s, 1e-6f);
    }
    __syncthreads();
    const int lc = (t & 15) * 4;        // col offset within 64
    const int rg = t >> 4;              // 0..15 row-group
    const int c0 = ck * 64;
    float sx = 0.f, sy = 0.f, sz = 0.f, sw = 0.f;
    for (int r = rg; r < Nn; r += 16) {
        float4 v = *(const float4*)(adj + ((size_t)b * Nn + r) * Nn + c0 + lc);
        float w = invdeg[r];
        sx += v.x * w; sy += v.y * w; sz += v.z * w; sw += v.w * w;
    }
    part[rg][lc + 0] = sx; part[rg][lc + 1] = sy;
    part[rg][lc + 2] = sz; part[rg][lc + 3] = sw;
    __syncthreads();
    if (t < 64) {
        float s = 0.f;
        #pragma unroll
        for (int g = 0; g < 16; ++g) s += part[g][t];
        csL[t] = s;
        colsum[b * Nn + c0 + t] = s;
    }
    __syncthreads();
    // gpre partial over this chunk's 64 rows of proj
    float g = 0.f;
    #pragma unroll 4
    for (int m = 0; m < 64; ++m)
        g += csL[m] * bf2f(proj_bf[((size_t)(b * Nn + c0 + m)) * Dn + t]);
    gpart[(b * 32 + ck) * Dn + t] = g;
}

// ---- K4: reduce partials -> matvecs -> LayerNorm -> out --------------------

__global__ __launch_bounds__(256) void k_final2(
    const float* __restrict__ gpart, const float* __restrict__ xpart,
    const float* __restrict__ W_rp, const float* __restrict__ b_rp,
    const float* __restrict__ W_gp, const float* __restrict__ b_gp,
    const float* __restrict__ gamma, const float* __restrict__ beta,
    float* __restrict__ out) {
    int b = blockIdx.x, t = threadIdx.x;
    __shared__ float gp_s[Dn];
    __shared__ float g1_s[Dn];
    __shared__ float red[8];
    float gs = 0.f, xs = 0.f;
    #pragma unroll
    for (int ck = 0; ck < 32; ++ck) {
        gs += gpart[(b * 32 + ck) * Dn + t];
        xs += xpart[(b * 32 + ck) * Dn + t];
    }
    gp_s[t] = gs * (1.0f / Nn);
    float xm = xs * (1.0f / Nn);
    __syncthreads();
    float g1 = b_rp[t];
    #pragma unroll 4
    for (int d = 0; d < Dn; ++d) g1 += gp_s[d] * W_rp[d * Dn + t];
    g1_s[t] = g1;
    __syncthreads();
    float g2 = b_gp[t];
    #pragma unroll 4
    for (int e = 0; e < Dn; ++e) g2 += g1_s[e] * W_gp[e * Dn + t];
    float h = g2 + xm;
    float sum = h;
    #pragma unroll
    for (int m = 1; m < 64; m <<= 1) sum += __shfl_xor(sum, m);
    if ((t & 63) == 0) red[t >> 6] = sum;
    __syncthreads();
    float mu = (red[0] + red[1] + red[2] + red[3]) * (1.0f / Dn);
    float dv = h - mu;
    float s2 = dv * dv;
    #pragma unroll
    for (int m = 1; m < 64; m <<= 1) s2 += __shfl_xor(s2, m);
    if ((t & 63) == 0) red[4 + (t >> 6)] = s2;
    __syncthreads();
    float var = (red[4] + red[5] + red[6] + red[7]) * (1.0f / Dn);
    out[b * Dn + t] = dv * rsqrtf(var + 1e-5f) * gamma[t] + beta[t];
}

// ---- launcher --------------------------------------------------------------

extern "C" void kernel_launch(void* const* d_in, const int* in_sizes, int n_in,
                              void* d_out, int out_size, void* d_ws, size_t ws_size,
                              hipStream_t stream) {
    const float* x     = (const float*)d_in[0];
    const float* W_fp  = (const float*)d_in[1];
    const float* b_fp  = (const float*)d_in[2];
    const float* w_s   = (const float*)d_in[3];
    const float* b_s   = (const float*)d_in[4];
    const float* W_rp  = (const float*)d_in[5];
    const float* b_rp  = (const float*)d_in[6];
    const float* W_gp  = (const float*)d_in[7];
    const float* b_gp  = (const float*)d_in[8];
    const float* gamma = (const float*)d_in[9];
    const float* beta  = (const float*)d_in[10];

    float* out = (float*)d_out;
    float* adj = out + Bn * Dn;   // outputs concatenated: out (B*D) then adj (B*N*N)

    char* ws = (char*)d_ws;
    short* proj_bf = (short*)(ws);                 // 8 MB
    short* xn      = (short*)(ws + 8388608);       // 8 MB
    short* Wt      = (short*)(ws + 16777216);      // 128 KB
    float* sdot    = (float*)(ws + 16908288);      // 64 KB
    float* degp    = (float*)(ws + 16973824);      // 1 MB
    float* colsum  = (float*)(ws + 18022400);      // 64 KB
    float* gpart   = (float*)(ws + 18087936);      // 256 KB
    float* xpart   = (float*)(ws + 18350080);      // 256 KB

    k_transpose<<<Dn, Dn, 0, stream>>>(W_fp, Wt);
    k_projxn<<<(Bn * Nn) / 64, 256, 0, stream>>>(x, Wt, b_fp, w_s, proj_bf, xn, sdot);
    k_xpart<<<dim3(Bn, 32), Dn, 0, stream>>>(x, xpart);
    k_sim<<<dim3(Nn / 128, Nn / 128, Bn), 256, 0, stream>>>(xn, sdot, b_s, adj, degp);
    k_colsum<<<dim3(Bn, 32), 256, 0, stream>>>(adj, degp, proj_bf, colsum, gpart);
    k_final2<<<Bn, 256, 0, stream>>>(gpart, xpart, W_rp, b_rp, W_gp, b_gp, gamma, beta, out);
}

// Round 4
// 287.719 us; speedup vs baseline: 1.3235x; 1.0971x over previous
//
#include <hip/hip_runtime.h>
#include <hip/hip_bf16.h>
#include <math.h>

#define Bn 8
#define Nn 2048
#define Dn 256

typedef short short8 __attribute__((ext_vector_type(8)));
typedef float floatx4 __attribute__((ext_vector_type(4)));

__device__ __forceinline__ short f2bf_bits(float f) {
    __bf16 h = (__bf16)f;
    return __builtin_bit_cast(short, h);
}

__device__ __forceinline__ float bf2f(short s) {
    unsigned u = ((unsigned)(unsigned short)s) << 16;
    return __builtin_bit_cast(float, u);
}

__device__ __forceinline__ void gl_lds16(const void* gsrc, void* ldst) {
    __builtin_amdgcn_global_load_lds(
        (const __attribute__((address_space(1))) void*)gsrc,
        (__attribute__((address_space(3))) void*)ldst, 16, 0, 0);
}

__device__ __forceinline__ float sigmoidf_(float z) {
    return 1.0f / (1.0f + __expf(-z));
}

// ---- Wt[e][d] = bf16(W_fp[d][e]) ------------------------------------------

__global__ void k_transpose(const float* __restrict__ W, short* __restrict__ Wt) {
    int e = blockIdx.x, d = threadIdx.x;
    Wt[e * Dn + d] = f2bf_bits(W[d * Dn + e]);
}

// ---- K1: proj rows (64 x 256 per block) via MFMA; fused norm, xn, sdot,
//          and x column-sum partials (xpart) from the staged A tiles. --------

__global__ __launch_bounds__(256) void k_projxn(
    const float* __restrict__ x, const short* __restrict__ Wt,
    const float* __restrict__ b_fp, const float* __restrict__ w_s,
    short* __restrict__ xn, float* __restrict__ sdot, float* __restrict__ nrm,
    float* __restrict__ xpart) {
    __shared__ __align__(16) short As[64 * 64];    // 8 KB
    __shared__ __align__(16) short Bs[256 * 64];   // 32 KB
    __shared__ float xsumS[4 * 256];               // 4 KB  [wave][d]
    const int t = threadIdx.x;
    const int bm = blockIdx.x * 64;                // global row base in [0, B*N)
    const int lane = t & 63, wv = t >> 6;
    const int wm = wv * 16;                        // wave's 16-row slab
    const int l15 = lane & 15, q = lane >> 4;

    for (int i = t; i < 1024; i += 256) xsumS[i] = 0.f;

    floatx4 acc[16];
    #pragma unroll
    for (int j = 0; j < 16; ++j) acc[j] = (floatx4){0.f, 0.f, 0.f, 0.f};

    const int rA = t >> 2, cA = (t & 3) * 16;      // A staging map
    const int rB = t >> 3, cB = (t & 7) * 8;       // B staging map

    for (int k0 = 0; k0 < Dn; k0 += 64) {
        // A: 64x64 fp32 -> bf16
        const float* gp = x + (size_t)(bm + rA) * Dn + k0 + cA;
        float4 v0 = *(const float4*)gp;
        float4 v1 = *(const float4*)(gp + 4);
        float4 v2 = *(const float4*)(gp + 8);
        float4 v3 = *(const float4*)(gp + 12);
        short8 o0, o1;
        o0[0] = f2bf_bits(v0.x); o0[1] = f2bf_bits(v0.y);
        o0[2] = f2bf_bits(v0.z); o0[3] = f2bf_bits(v0.w);
        o0[4] = f2bf_bits(v1.x); o0[5] = f2bf_bits(v1.y);
        o0[6] = f2bf_bits(v1.z); o0[7] = f2bf_bits(v1.w);
        o1[0] = f2bf_bits(v2.x); o1[1] = f2bf_bits(v2.y);
        o1[2] = f2bf_bits(v2.z); o1[3] = f2bf_bits(v2.w);
        o1[4] = f2bf_bits(v3.x); o1[5] = f2bf_bits(v3.y);
        o1[6] = f2bf_bits(v3.z); o1[7] = f2bf_bits(v3.w);
        *(short8*)(As + rA * 64 + cA) = o0;
        *(short8*)(As + rA * 64 + cA + 8) = o1;
        // B: Wt slice 256x64 via async global->LDS
        #pragma unroll
        for (int cc = 0; cc < 8; ++cc)
            gl_lds16(Wt + (size_t)(cc * 32 + rB) * Dn + k0 + cB,
                     Bs + (cc * 32 + rB) * 64 + cB);
        __syncthreads();
        #pragma unroll
        for (int ks = 0; ks < 2; ++ks) {
            short8 af = *(const short8*)(As + (wm + l15) * 64 + ks * 32 + q * 8);
            #pragma unroll
            for (int j = 0; j < 16; ++j) {
                short8 bfr = *(const short8*)(Bs + (j * 16 + l15) * 64 + ks * 32 + q * 8);
                acc[j] = __builtin_amdgcn_mfma_f32_16x16x32_bf16(af, bfr, acc[j], 0, 0, 0);
            }
        }
        // fused x column-sum: wave wv sums its 16 rows for column `lane`
        {
            float s = 0.f;
            #pragma unroll
            for (int r = 0; r < 16; ++r)
                s += bf2f(As[(wm + r) * 64 + lane]);
            xsumS[wv * 256 + k0 + lane] += s;
        }
        __syncthreads();
    }
    // xpart fold (all waves' partials visible after last sync)
    {
        float xs = xsumS[t] + xsumS[256 + t] + xsumS[512 + t] + xsumS[768 + t];
        xpart[(size_t)blockIdx.x * Dn + t] = xs;
    }
    // epilogue: per reg, one full row per 16-lane group
    float bfv[16], wsv[16];
    #pragma unroll
    for (int j = 0; j < 16; ++j) {
        bfv[j] = b_fp[j * 16 + l15];
        wsv[j] = w_s[j * 16 + l15];
    }
    #pragma unroll
    for (int reg = 0; reg < 4; ++reg) {
        int row = bm + wm + q * 4 + reg;
        float v[16];
        float pw = 0.f, pn = 0.f;
        #pragma unroll
        for (int j = 0; j < 16; ++j) {
            v[j] = acc[j][reg] + bfv[j];
            pw += v[j] * wsv[j];
            pn += v[j] * v[j];
        }
        #pragma unroll
        for (int m = 1; m < 16; m <<= 1) {
            pw += __shfl_xor(pw, m);
            pn += __shfl_xor(pn, m);
        }
        float nc = fmaxf(sqrtf(pn), 1e-12f);
        float inv = 1.0f / nc;
        size_t rbase = (size_t)row * Dn + l15;
        #pragma unroll
        for (int j = 0; j < 16; ++j)
            xn[rbase + j * 16] = f2bf_bits(v[j] * inv);
        if (l15 == 0) {
            sdot[row] = pw;
            nrm[row] = nc;
        }
    }
}

// ---- K2: sim = xn@xn^T, scaler/clamp, adj write, per-tile degree partials --

__global__ __launch_bounds__(256) void k_sim(
    const short* __restrict__ xn, const float* __restrict__ sdot,
    const float* __restrict__ b_s, float* __restrict__ adj,
    float* __restrict__ deg_part) {
    __shared__ __align__(16) short As[128 * 64];
    __shared__ __align__(16) short Bs[128 * 64];
    __shared__ float degS[2][128];
    const int t = threadIdx.x;
    const int cx = blockIdx.x;
    const int bn = cx * 128;           // col tile
    const int bm = blockIdx.y * 128;   // row tile
    const int b = blockIdx.z;
    const int lane = t & 63, wv = t >> 6;
    const int wm = (wv >> 1) * 64, wn = (wv & 1) * 64;
    const int l15 = lane & 15, q = lane >> 4;
    const int rr = t >> 3, c8 = (t & 7) * 8;
    const short* xb = xn + (size_t)b * Nn * Dn;

    floatx4 acc[4][4];
    #pragma unroll
    for (int i = 0; i < 4; ++i)
        #pragma unroll
        for (int j = 0; j < 4; ++j) acc[i][j] = (floatx4){0.f, 0.f, 0.f, 0.f};

    for (int k0 = 0; k0 < Dn; k0 += 64) {
        #pragma unroll
        for (int cc = 0; cc < 4; ++cc) {
            int r = cc * 32 + rr;
            gl_lds16(xb + (size_t)(bm + r) * Dn + k0 + c8, As + r * 64 + c8);
            gl_lds16(xb + (size_t)(bn + r) * Dn + k0 + c8, Bs + r * 64 + c8);
        }
        __syncthreads();
        #pragma unroll
        for (int ks = 0; ks < 2; ++ks) {
            short8 af[4], bfr[4];
            #pragma unroll
            for (int i = 0; i < 4; ++i)
                af[i] = *(const short8*)(As + (wm + i * 16 + l15) * 64 + ks * 32 + q * 8);
            #pragma unroll
            for (int j = 0; j < 4; ++j)
                bfr[j] = *(const short8*)(Bs + (wn + j * 16 + l15) * 64 + ks * 32 + q * 8);
            #pragma unroll
            for (int i = 0; i < 4; ++i)
                #pragma unroll
                for (int j = 0; j < 4; ++j)
                    acc[i][j] = __builtin_amdgcn_mfma_f32_16x16x32_bf16(af[i], bfr[j], acc[i][j], 0, 0, 0);
        }
        __syncthreads();
    }
    // epilogue
    const float bsv = b_s[0];
    float scol[4];
    #pragma unroll
    for (int j = 0; j < 4; ++j)
        scol[j] = sigmoidf_(sdot[b * Nn + bn + wn + j * 16 + l15] + bsv);
    #pragma unroll
    for (int i = 0; i < 4; ++i) {
        #pragma unroll
        for (int reg = 0; reg < 4; ++reg) {
            int lr = wm + i * 16 + q * 4 + reg;     // local row 0..127
            int row = bm + lr;
            float srow = sigmoidf_(sdot[b * Nn + row] + bsv);
            size_t obase = ((size_t)b * Nn + row) * Nn + bn + wn + l15;
            float rs = 0.f;
            #pragma unroll
            for (int j = 0; j < 4; ++j) {
                float sc = 0.5f * (srow + scol[j]);
                sc = fminf(fmaxf(sc, 1e-6f), 1.0f);
                float v = fmaxf(sc * acc[i][j][reg], 1e-6f);
                adj[obase + (size_t)j * 16] = v;
                rs += v;
            }
            #pragma unroll
            for (int m = 1; m < 16; m <<= 1) rs += __shfl_xor(rs, m);
            if (l15 == 0) degS[wv & 1][lr] = rs;
        }
    }
    __syncthreads();
    if (t < 128)
        deg_part[((size_t)(b * 16 + cx)) * Nn + bm + t] = degS[0][t] + degS[1][t];
}

// ---- K3: colsum chunk (no atomics) + fused gpre partial ---------------------
// block (b, ck): cols ck*64..+63, all 2048 rows; 512 threads for occupancy.
// gpart[b][ck][d] = sum_{m in chunk} cs[m]*nrm[m]*xn[m,d]  (proj = nrm*xn)

__global__ __launch_bounds__(512) void k_colsum(
    const float* __restrict__ adj, const float* __restrict__ deg_part,
    const short* __restrict__ xn, const float* __restrict__ nrm,
    float* __restrict__ gpart) {
    int b = blockIdx.x, ck = blockIdx.y, t = threadIdx.x;
    __shared__ float invdeg[Nn];        // 8 KB
    __shared__ float part[32][64];      // 8 KB
    __shared__ float csL[64];
    #pragma unroll
    for (int rc = 0; rc < 4; ++rc) {
        int row = rc * 512 + t;
        float s = 0.f;
        #pragma unroll
        for (int cx = 0; cx < 16; ++cx)
            s += deg_part[((size_t)(b * 16 + cx)) * Nn + row];
        invdeg[row] = 1.0f / fmaxf(s, 1e-6f);
    }
    __syncthreads();
    const int lc = (t & 15) * 4;        // col offset within 64
    const int rg = t >> 4;              // 0..31 row-group
    const int c0 = ck * 64;
    float sx = 0.f, sy = 0.f, sz = 0.f, sw = 0.f;
    for (int r = rg; r < Nn; r += 32) {
        float4 v = *(const float4*)(adj + ((size_t)b * Nn + r) * Nn + c0 + lc);
        float w = invdeg[r];
        sx += v.x * w; sy += v.y * w; sz += v.z * w; sw += v.w * w;
    }
    part[rg][lc + 0] = sx; part[rg][lc + 1] = sy;
    part[rg][lc + 2] = sz; part[rg][lc + 3] = sw;
    __syncthreads();
    if (t < 64) {
        float s = 0.f;
        #pragma unroll
        for (int g = 0; g < 32; ++g) s += part[g][t];
        csL[t] = s * nrm[b * Nn + c0 + t];   // fold proj = nrm * xn
    }
    __syncthreads();
    if (t < Dn) {
        float g = 0.f;
        #pragma unroll 4
        for (int m = 0; m < 64; ++m)
            g += csL[m] * bf2f(xn[((size_t)(b * Nn + c0 + m)) * Dn + t]);
        gpart[(b * 32 + ck) * Dn + t] = g;
    }
}

// ---- K4: reduce partials -> matvecs -> LayerNorm -> out --------------------

__global__ __launch_bounds__(256) void k_final2(
    const float* __restrict__ gpart, const float* __restrict__ xpart,
    const float* __restrict__ W_rp, const float* __restrict__ b_rp,
    const float* __restrict__ W_gp, const float* __restrict__ b_gp,
    const float* __restrict__ gamma, const float* __restrict__ beta,
    float* __restrict__ out) {
    int b = blockIdx.x, t = threadIdx.x;
    __shared__ float gp_s[Dn];
    __shared__ float g1_s[Dn];
    __shared__ float red[8];
    float gs = 0.f, xs = 0.f;
    #pragma unroll
    for (int ck = 0; ck < 32; ++ck) {
        gs += gpart[(b * 32 + ck) * Dn + t];
        xs += xpart[(b * 32 + ck) * Dn + t];
    }
    gp_s[t] = gs * (1.0f / Nn);
    float xm = xs * (1.0f / Nn);
    __syncthreads();
    float g1 = b_rp[t];
    #pragma unroll 4
    for (int d = 0; d < Dn; ++d) g1 += gp_s[d] * W_rp[d * Dn + t];
    g1_s[t] = g1;
    __syncthreads();
    float g2 = b_gp[t];
    #pragma unroll 4
    for (int e = 0; e < Dn; ++e) g2 += g1_s[e] * W_gp[e * Dn + t];
    float h = g2 + xm;
    float sum = h;
    #pragma unroll
    for (int m = 1; m < 64; m <<= 1) sum += __shfl_xor(sum, m);
    if ((t & 63) == 0) red[t >> 6] = sum;
    __syncthreads();
    float mu = (red[0] + red[1] + red[2] + red[3]) * (1.0f / Dn);
    float dv = h - mu;
    float s2 = dv * dv;
    #pragma unroll
    for (int m = 1; m < 64; m <<= 1) s2 += __shfl_xor(s2, m);
    if ((t & 63) == 0) red[4 + (t >> 6)] = s2;
    __syncthreads();
    float var = (red[4] + red[5] + red[6] + red[7]) * (1.0f / Dn);
    out[b * Dn + t] = dv * rsqrtf(var + 1e-5f) * gamma[t] + beta[t];
}

// ---- launcher --------------------------------------------------------------

extern "C" void kernel_launch(void* const* d_in, const int* in_sizes, int n_in,
                              void* d_out, int out_size, void* d_ws, size_t ws_size,
                              hipStream_t stream) {
    const float* x     = (const float*)d_in[0];
    const float* W_fp  = (const float*)d_in[1];
    const float* b_fp  = (const float*)d_in[2];
    const float* w_s   = (const float*)d_in[3];
    const float* b_s   = (const float*)d_in[4];
    const float* W_rp  = (const float*)d_in[5];
    const float* b_rp  = (const float*)d_in[6];
    const float* W_gp  = (const float*)d_in[7];
    const float* b_gp  = (const float*)d_in[8];
    const float* gamma = (const float*)d_in[9];
    const float* beta  = (const float*)d_in[10];

    float* out = (float*)d_out;
    float* adj = out + Bn * Dn;   // outputs concatenated: out (B*D) then adj (B*N*N)

    char* ws = (char*)d_ws;
    short* xn    = (short*)(ws);                 // 8 MB
    short* Wt    = (short*)(ws + 8388608);       // 128 KB
    float* sdot  = (float*)(ws + 8519680);       // 64 KB
    float* nrm   = (float*)(ws + 8585216);       // 64 KB
    float* degp  = (float*)(ws + 8650752);       // 1 MB
    float* gpart = (float*)(ws + 9699328);       // 256 KB
    float* xpart = (float*)(ws + 9961472);       // 256 KB

    k_transpose<<<Dn, Dn, 0, stream>>>(W_fp, Wt);
    k_projxn<<<(Bn * Nn) / 64, 256, 0, stream>>>(x, Wt, b_fp, w_s, xn, sdot, nrm, xpart);
    k_sim<<<dim3(Nn / 128, Nn / 128, Bn), 256, 0, stream>>>(xn, sdot, b_s, adj, degp);
    k_colsum<<<dim3(Bn, 32), 512, 0, stream>>>(adj, degp, xn, nrm, gpart);
    k_final2<<<Bn, 256, 0, stream>>>(gpart, xpart, W_rp, b_rp, W_gp, b_gp, gamma, beta, out);
}